// Round 2
// baseline (1321.254 us; speedup 1.0000x reference)
//
#include <hip/hip_runtime.h>
#include <cstdint>
#include <cstddef>

#define HD 128
#define NEG_SLOPE 0.2f
#define BN_EPS 1e-5f

// =============================================================================
// GEMM: out[M,128] = X[M,K] @ W[K,128]   (mode 0: plain -> h)
// mode 1: out = relu((acc + fb)*(fg/sqrt(1+eps)) + fbeta) + gb
//         (feature_transform incl. its relu, fused with GAT bias; the final
//          layer relu(gat+y) happens in agg_kernel)
// Tile: 64(M) x 128(N), TK=16, 256 threads, each thread 4x8 outputs.
// =============================================================================
__global__ __launch_bounds__(256) void gemm128(
    const float* __restrict__ X, const float* __restrict__ W,
    float* __restrict__ out, int M, int K, int mode,
    const float* __restrict__ fb, const float* __restrict__ fg,
    const float* __restrict__ fbeta, const float* __restrict__ gb)
{
    __shared__ float As[16][68];    // transposed A tile, padded row=68
    __shared__ float Bs[16][128];
    const int tid  = threadIdx.x;
    const int row0 = blockIdx.x * 64;
    const int tn = tid & 15;          // 16 col groups * 8 cols
    const int tm = tid >> 4;          // 16 row groups * 4 rows
    const int ar = tid >> 2;          // A stage: row within tile (0..63)
    const int ak = (tid & 3) * 4;     //          k offset (float4 along K)
    const int brow = tid >> 5;        // B stage: k row 0..7 (+8 for 2nd load)
    const int bcol = (tid & 31) * 4;

    float acc[4][8];
#pragma unroll
    for (int r = 0; r < 4; r++)
#pragma unroll
        for (int c = 0; c < 8; c++) acc[r][c] = 0.f;

    int arow = row0 + ar; if (arow >= M) arow = M - 1;

    for (int k0 = 0; k0 < K; k0 += 16) {
        float4 av  = *(const float4*)(X + (size_t)arow * K + k0 + ak);
        float4 bv0 = *(const float4*)(W + (size_t)(k0 + brow) * HD + bcol);
        float4 bv1 = *(const float4*)(W + (size_t)(k0 + 8 + brow) * HD + bcol);
        __syncthreads();
        As[ak + 0][ar] = av.x; As[ak + 1][ar] = av.y;
        As[ak + 2][ar] = av.z; As[ak + 3][ar] = av.w;
        *(float4*)&Bs[brow][bcol]     = bv0;
        *(float4*)&Bs[brow + 8][bcol] = bv1;
        __syncthreads();
#pragma unroll
        for (int k = 0; k < 16; k++) {
            float4 a  = *(const float4*)&As[k][tm * 4];
            float4 b0 = *(const float4*)&Bs[k][tn * 8];
            float4 b1 = *(const float4*)&Bs[k][tn * 8 + 4];
            float as[4] = {a.x, a.y, a.z, a.w};
            float bs[8] = {b0.x, b0.y, b0.z, b0.w, b1.x, b1.y, b1.z, b1.w};
#pragma unroll
            for (int r = 0; r < 4; r++)
#pragma unroll
                for (int c = 0; c < 8; c++) acc[r][c] += as[r] * bs[c];
        }
    }

    const int ncol = tn * 8;
    if (mode == 0) {
#pragma unroll
        for (int r = 0; r < 4; r++) {
            int row = row0 + tm * 4 + r;
            if (row < M) {
                float4 o0 = {acc[r][0], acc[r][1], acc[r][2], acc[r][3]};
                float4 o1 = {acc[r][4], acc[r][5], acc[r][6], acc[r][7]};
                *(float4*)(out + (size_t)row * HD + ncol)     = o0;
                *(float4*)(out + (size_t)row * HD + ncol + 4) = o1;
            }
        }
    } else {
        float g[8], bb[8], bt[8], gv[8];
        const float inv_bn = 1.0f / sqrtf(1.0f + BN_EPS);
#pragma unroll
        for (int c = 0; c < 8; c++) {
            g[c]  = fg[ncol + c] * inv_bn;
            bb[c] = fb[ncol + c];
            bt[c] = fbeta[ncol + c];
            gv[c] = gb[ncol + c];
        }
#pragma unroll
        for (int r = 0; r < 4; r++) {
            int row = row0 + tm * 4 + r;
            if (row < M) {
                float o[8];
#pragma unroll
                for (int c = 0; c < 8; c++) {
                    float y = (acc[r][c] + bb[c]) * g[c] + bt[c];
                    y = y > 0.f ? y : 0.f;          // relu(y) BEFORE adding gat bias
                    o[c] = y + gv[c];
                }
                float4 o0 = {o[0], o[1], o[2], o[3]}, o1 = {o[4], o[5], o[6], o[7]};
                *(float4*)(out + (size_t)row * HD + ncol)     = o0;
                *(float4*)(out + (size_t)row * HD + ncol + 4) = o1;
            }
        }
    }
}

// ============================ attention logits ===============================
// al_s[n,h] = dot(h[n,h,:], a_src[h,:]),  al_d likewise.  One thread per (n,h).
__global__ void al_kernel(const float* __restrict__ h, const float* __restrict__ a_src,
                          const float* __restrict__ a_dst,
                          float* __restrict__ als, float* __restrict__ ald, int N)
{
    int t = blockIdx.x * blockDim.x + threadIdx.x;
    if (t >= N * 4) return;
    int n = t >> 2, hd = t & 3;
    const float* hp = h + (size_t)n * HD + hd * 32;
    const float* as = a_src + hd * 32;
    const float* ad = a_dst + hd * 32;
    float s1 = 0.f, s2 = 0.f;
#pragma unroll
    for (int i = 0; i < 32; i += 4) {
        float4 hv = *(const float4*)(hp + i);
        float4 av = *(const float4*)(as + i);
        float4 dv = *(const float4*)(ad + i);
        s1 += hv.x * av.x + hv.y * av.y + hv.z * av.z + hv.w * av.w;
        s2 += hv.x * dv.x + hv.y * dv.y + hv.z * dv.z + hv.w * dv.w;
    }
    als[t] = s1; ald[t] = s2;
}

// ============================ CSR build (once) ===============================
__global__ void hist_kernel(const int* __restrict__ ei, int E, int N, int* __restrict__ deg)
{
    int t = blockIdx.x * blockDim.x + threadIdx.x;
    if (t >= E + N) return;
    int d = (t < E) ? ei[E + t] : (t - E);   // self loops appended
    atomicAdd(&deg[d], 1);
}

__global__ void scan1(const int* __restrict__ deg, int* __restrict__ rp,
                      int* __restrict__ bsum, int N)
{
    __shared__ int sh[256];
    int t = threadIdx.x;
    int i0 = blockIdx.x * 1024 + t * 4;
    int v[4];
#pragma unroll
    for (int j = 0; j < 4; j++) v[j] = (i0 + j < N) ? deg[i0 + j] : 0;
    int tot = v[0] + v[1] + v[2] + v[3];
    sh[t] = tot;
    __syncthreads();
    for (int off = 1; off < 256; off <<= 1) {
        int xv = (t >= off) ? sh[t - off] : 0;
        __syncthreads();
        sh[t] += xv;
        __syncthreads();
    }
    int run = sh[t] - tot;   // exclusive prefix of this thread
    if (t == 255) bsum[blockIdx.x] = sh[255];
#pragma unroll
    for (int j = 0; j < 4; j++) {
        if (i0 + j < N) rp[i0 + j] = run;
        run += v[j];
    }
}

__global__ void scan2(int* __restrict__ bsum, int nb)
{
    if (threadIdx.x == 0 && blockIdx.x == 0) {
        int run = 0;
        for (int i = 0; i < nb; i++) { int v = bsum[i]; bsum[i] = run; run += v; }
    }
}

__global__ void scan3(int* __restrict__ rp, int* __restrict__ cur,
                      const int* __restrict__ bsum, int N, int Etot)
{
    int t = blockIdx.x * blockDim.x + threadIdx.x;
    if (t < N) {
        int v = rp[t] + bsum[t >> 10];
        rp[t] = v;
        cur[t] = v;
    } else if (t == N) {
        rp[N] = Etot;
    }
}

__global__ void scatter_kernel(const int* __restrict__ ei, int E, int N,
                               int* __restrict__ cur, int* __restrict__ col)
{
    int t = blockIdx.x * blockDim.x + threadIdx.x;
    if (t >= E + N) return;
    int s, d;
    if (t < E) { s = ei[t]; d = ei[E + t]; } else { s = t - E; d = t - E; }
    int p = atomicAdd(&cur[d], 1);
    col[p] = s;
}

// ============================ aggregation ====================================
// One wave per dst node. Softmax (max, sum) via in-wave shuffle reductions over
// (16 edge-lanes x 4 head-lanes); accumulation: lane owns channels {lane, lane+64}.
// xio holds relu(y)+gb; we add the GAT aggregate and apply the layer relu in place.
__global__ __launch_bounds__(256) void agg_kernel(
    const float* __restrict__ h, const float* __restrict__ als,
    const float* __restrict__ ald, const int* __restrict__ rp,
    const int* __restrict__ col, float* __restrict__ xio, int N)
{
    int wid  = (blockIdx.x * blockDim.x + threadIdx.x) >> 6;
    int lane = threadIdx.x & 63;
    if (wid >= N) return;
    int beg = rp[wid], end = rp[wid + 1];
    int deg = end - beg;

    // phase A: per-head max and sum-exp. lane -> (edge j = lane>>2, head = lane&3)
    int hA = lane & 3;
    float adA = ald[wid * 4 + hA];
    float m = -1e30f;
    for (int j = lane >> 2; j < deg; j += 16) {
        int s = col[beg + j];
        float e = als[s * 4 + hA] + adA;
        e = e > 0.f ? e : NEG_SLOPE * e;
        m = fmaxf(m, e);
    }
#pragma unroll
    for (int off = 4; off < 64; off <<= 1) m = fmaxf(m, __shfl_xor(m, off));
    float ss = 0.f;
    for (int j = lane >> 2; j < deg; j += 16) {
        int s = col[beg + j];
        float e = als[s * 4 + hA] + adA;
        e = e > 0.f ? e : NEG_SLOPE * e;
        ss += __expf(e - m);
    }
#pragma unroll
    for (int off = 4; off < 64; off <<= 1) ss += __shfl_xor(ss, off);
    float inv = 1.0f / ss;

    // phase B: lane's channels c0=lane (head h0), c1=lane+64 (head h1=2+h0)
    int h0 = lane >> 5, h1 = 2 + h0;
    float m0 = __shfl(m, h0),  m1 = __shfl(m, h1);     // lanes 0..3 hold heads 0..3
    float i0 = __shfl(inv, h0), i1 = __shfl(inv, h1);
    float ad0 = ald[wid * 4 + h0], ad1 = ald[wid * 4 + h1];
    float acc0 = 0.f, acc1 = 0.f;
    for (int j = beg; j < end; j++) {
        int s = col[j];
        float e0 = als[s * 4 + h0] + ad0; e0 = e0 > 0.f ? e0 : NEG_SLOPE * e0;
        float e1 = als[s * 4 + h1] + ad1; e1 = e1 > 0.f ? e1 : NEG_SLOPE * e1;
        float w0 = __expf(e0 - m0) * i0;
        float w1 = __expf(e1 - m1) * i1;
        const float* hp = h + (size_t)s * HD;
        acc0 += w0 * hp[lane];
        acc1 += w1 * hp[64 + lane];
    }
    float* xp = xio + (size_t)wid * HD;
    float v0 = acc0 + xp[lane];
    float v1 = acc1 + xp[64 + lane];
    xp[lane]      = v0 > 0.f ? v0 : 0.f;
    xp[64 + lane] = v1 > 0.f ? v1 : 0.f;
}

// ============================ classifier =====================================
// One wave per row: split-K over lanes (k = lane, lane+64), butterfly-reduce 10 sums.
__global__ __launch_bounds__(256) void cls_kernel(
    const float* __restrict__ x, const float* __restrict__ w,
    const float* __restrict__ b, float* __restrict__ out, int N)
{
    int wid  = (blockIdx.x * blockDim.x + threadIdx.x) >> 6;
    int lane = threadIdx.x & 63;
    if (wid >= N) return;
    float x0 = x[(size_t)wid * HD + lane];
    float x1 = x[(size_t)wid * HD + 64 + lane];
    float acc[10];
#pragma unroll
    for (int o = 0; o < 10; o++)
        acc[o] = x0 * w[lane * 10 + o] + x1 * w[(lane + 64) * 10 + o];
#pragma unroll
    for (int o = 0; o < 10; o++) {
        float v = acc[o];
#pragma unroll
        for (int off = 1; off < 64; off <<= 1) v += __shfl_xor(v, off);
        acc[o] = v;
    }
    float v = 0.f;
#pragma unroll
    for (int o = 0; o < 10; o++) if (lane == o) v = acc[o];
    if (lane < 10) out[(size_t)wid * 10 + lane] = v + b[lane];
}

// =============================================================================
extern "C" void kernel_launch(void* const* d_in, const int* in_sizes, int n_in,
                              void* d_out, int out_size, void* d_ws, size_t ws_size,
                              hipStream_t stream)
{
    const float* x0 = (const float*)d_in[0];
    const int*   ei = (const int*)d_in[1];      // [2,E] int32
    const int N = in_sizes[0] / 512;
    const int E = in_sizes[1] / 2;
    const int Etot = E + N;

    const float *gw[3], *gas[3], *gad[3], *gbp[3], *fw[3], *fbp[3], *fgp[3], *fbt[3];
    for (int l = 0; l < 3; l++) {
        int b = 3 + 8 * l;
        gw[l]  = (const float*)d_in[b + 0];
        gas[l] = (const float*)d_in[b + 1];
        gad[l] = (const float*)d_in[b + 2];
        gbp[l] = (const float*)d_in[b + 3];
        fw[l]  = (const float*)d_in[b + 4];
        fbp[l] = (const float*)d_in[b + 5];
        fgp[l] = (const float*)d_in[b + 6];
        fbt[l] = (const float*)d_in[b + 7];
    }
    const float* cw = (const float*)d_in[27];
    const float* cb = (const float*)d_in[28];

    // workspace carve (aligned 256B): xA, xB, h [N,128] f32; als/ald [N,4]; CSR ints
    char* p = (char*)d_ws;
    auto carve = [&](size_t bytes) -> char* {
        char* r = p; p += (bytes + 255) & ~(size_t)255; return r;
    };
    float* xA   = (float*)carve((size_t)N * HD * 4);
    float* xB   = (float*)carve((size_t)N * HD * 4);
    float* hbuf = (float*)carve((size_t)N * HD * 4);
    float* als  = (float*)carve((size_t)N * 4 * 4);
    float* ald  = (float*)carve((size_t)N * 4 * 4);
    int* rp   = (int*)carve((size_t)(N + 1) * 4);
    int* deg  = (int*)carve((size_t)N * 4);
    int* cur  = (int*)carve((size_t)N * 4);
    int* bsum = (int*)carve(4096);
    int* col  = (int*)carve((size_t)Etot * 4);

    // ---- CSR by dst (built once per launch; graph constant across layers) ----
    hipMemsetAsync(deg, 0, (size_t)N * 4, stream);
    hist_kernel<<<(Etot + 255) / 256, 256, 0, stream>>>(ei, E, N, deg);
    int nb = (N + 1023) / 1024;
    scan1<<<nb, 256, 0, stream>>>(deg, rp, bsum, N);
    scan2<<<1, 64, 0, stream>>>(bsum, nb);
    scan3<<<(N + 256) / 256, 256, 0, stream>>>(rp, cur, bsum, N, Etot);
    scatter_kernel<<<(Etot + 255) / 256, 256, 0, stream>>>(ei, E, N, cur, col);

    // ---- 3 message-passing layers ----
    for (int l = 0; l < 3; l++) {
        const float* xin = (l == 0) ? x0 : ((l == 1) ? xA : xB);
        float* xout = (l == 1) ? xB : xA;   // relu(y)+gb lives here, agg updates in place
        int K = (l == 0) ? 512 : HD;
        int mblocks = (N + 63) / 64;
        gemm128<<<mblocks, 256, 0, stream>>>(xin, gw[l], hbuf, N, K, 0,
                                             nullptr, nullptr, nullptr, nullptr);
        al_kernel<<<(N * 4 + 255) / 256, 256, 0, stream>>>(hbuf, gas[l], gad[l], als, ald, N);
        gemm128<<<mblocks, 256, 0, stream>>>(xin, fw[l], xout, N, K, 1,
                                             fbp[l], fgp[l], fbt[l], gbp[l]);
        agg_kernel<<<(N + 3) / 4, 256, 0, stream>>>(hbuf, als, ald, rp, col, xout, N);
    }

    // ---- classifier ----
    cls_kernel<<<(N + 3) / 4, 256, 0, stream>>>(xA, cw, cb, (float*)d_out, N);
}

// Round 3
// 1015.391 us; speedup vs baseline: 1.3012x; 1.3012x over previous
//
#include <hip/hip_runtime.h>
#include <cstdint>
#include <cstddef>

#define HD 128
#define NEG_SLOPE 0.2f
#define BN_EPS 1e-5f

typedef __bf16 bf16x8 __attribute__((ext_vector_type(8)));
typedef float  f32x4  __attribute__((ext_vector_type(4)));

__device__ __forceinline__ unsigned short f2b(float f) {   // fp32 -> bf16 RNE
    unsigned int u = __float_as_uint(f);
    u = (u + 0x7fffu + ((u >> 16) & 1u)) >> 16;
    return (unsigned short)u;
}
__device__ __forceinline__ unsigned int pack2(float lo, float hi) {
    return (unsigned int)f2b(lo) | ((unsigned int)f2b(hi) << 16);
}

// =============================================================================
// Weight prep: W fp32 [K][128]  ->  Wt bf16 [128][K]   (cast + transpose, tiny)
// =============================================================================
__global__ void prep_w(const float* __restrict__ W, unsigned short* __restrict__ Wt, int K)
{
    int t = blockIdx.x * 256 + threadIdx.x;
    if (t >= K * 128) return;
    int k = t >> 7, c = t & 127;
    Wt[(size_t)c * K + k] = f2b(W[t]);
}

// =============================================================================
// MFMA bf16 GEMM: out[M,128] = X[M,K](fp32, cast on stage) @ Wt[128,K](bf16)
// mode 0: store bf16 h.  mode 1: out = relu((acc+fb)*g+fbeta)+gb, fp32.
// Tile 64(M) x 128(N), BK=32, 256 thr = 4 waves; wave w -> rows 16w..16w+15,
// 8 col-tiles of 16. Frags (verified layouts): A[m=lane&15][k=quad*8+j],
// B[k=quad*8+j][n=lane&15], D col=lane&15 row=quad*4+reg.
// =============================================================================
__global__ __launch_bounds__(256) void gemm_mfma(
    const float* __restrict__ X, const unsigned short* __restrict__ Wt,
    void* __restrict__ out, int M, int K, int mode,
    const float* __restrict__ fb, const float* __restrict__ fg,
    const float* __restrict__ fbeta, const float* __restrict__ gb)
{
    // LDS: As 64 rows x 40 bf16 (pad 32->40), Bs 128 rows x 40 bf16
    __shared__ __align__(16) char smem[64 * 80 + 128 * 80];
    char* Asb = smem;
    char* Bsb = smem + 64 * 80;

    const int tid  = threadIdx.x;
    const int row0 = blockIdx.x * 64;
    const int w    = tid >> 6;
    const int lane = tid & 63;
    const int m    = lane & 15;          // frag row/col within 16
    const int q    = lane >> 4;          // quad -> k chunk

    // staging indices
    const int ar = tid >> 2;             // A: row 0..63
    const int ak = (tid & 3) * 8;        //    k offset (8 floats)
    const int bn = tid >> 1;             // B: n row 0..127
    const int bk = (tid & 1) * 16;       //    k offset (16 bf16)

    int arow = row0 + ar; if (arow >= M) arow = M - 1;

    f32x4 acc[8];
#pragma unroll
    for (int t = 0; t < 8; t++) acc[t] = (f32x4){0.f, 0.f, 0.f, 0.f};

    const int aoff_w = (ar) * 80 + ak * 2;
    const int boff_w = bn * 80 + bk * 2;
    const int aoff_r = (16 * w + m) * 80 + q * 16;

    for (int ks = 0; ks < K; ks += 32) {
        const float* xr = X + (size_t)arow * K + ks + ak;
        float4 a0 = *(const float4*)xr;
        float4 a1 = *(const float4*)(xr + 4);
        const unsigned short* wr = Wt + (size_t)bn * K + ks + bk;
        uint4 b0 = *(const uint4*)wr;
        uint4 b1 = *(const uint4*)(wr + 8);
        __syncthreads();
        uint4 ap;
        ap.x = pack2(a0.x, a0.y); ap.y = pack2(a0.z, a0.w);
        ap.z = pack2(a1.x, a1.y); ap.w = pack2(a1.z, a1.w);
        *(uint4*)(Asb + aoff_w) = ap;
        *(uint4*)(Bsb + boff_w)      = b0;
        *(uint4*)(Bsb + boff_w + 16) = b1;
        __syncthreads();
        bf16x8 af = *(const bf16x8*)(Asb + aoff_r);
#pragma unroll
        for (int t = 0; t < 8; t++) {
            bf16x8 bf = *(const bf16x8*)(Bsb + (t * 16 + m) * 80 + q * 16);
            acc[t] = __builtin_amdgcn_mfma_f32_16x16x32_bf16(af, bf, acc[t], 0, 0, 0);
        }
    }

    // epilogue: lane holds D[row = row0+16w+q*4+r][col = t*16+m]
    if (mode == 0) {
        unsigned short* hb = (unsigned short*)out;
#pragma unroll
        for (int t = 0; t < 8; t++) {
            int col = t * 16 + m;
#pragma unroll
            for (int r = 0; r < 4; r++) {
                int row = row0 + 16 * w + q * 4 + r;
                if (row < M) hb[(size_t)row * HD + col] = f2b(acc[t][r]);
            }
        }
    } else {
        float* ob = (float*)out;
        const float inv_bn = 1.0f / sqrtf(1.0f + BN_EPS);
#pragma unroll
        for (int t = 0; t < 8; t++) {
            int col = t * 16 + m;
            float g  = fg[col] * inv_bn;
            float bb = fb[col];
            float bt = fbeta[col];
            float gv = gb[col];
#pragma unroll
            for (int r = 0; r < 4; r++) {
                int row = row0 + 16 * w + q * 4 + r;
                if (row < M) {
                    float y = (acc[t][r] + bb) * g + bt;
                    y = y > 0.f ? y : 0.f;       // feature_transform relu
                    ob[(size_t)row * HD + col] = y + gv;
                }
            }
        }
    }
}

// ============================ attention logits ===============================
// h is bf16 [N,128]. One thread per (n,head): 32-ch dots with a_src/a_dst.
__global__ void al_kernel(const unsigned short* __restrict__ h,
                          const float* __restrict__ a_src, const float* __restrict__ a_dst,
                          float* __restrict__ als, float* __restrict__ ald, int N)
{
    int t = blockIdx.x * blockDim.x + threadIdx.x;
    if (t >= N * 4) return;
    int n = t >> 2, hd = t & 3;
    const unsigned short* hp = h + (size_t)n * HD + hd * 32;
    const float* as = a_src + hd * 32;
    const float* ad = a_dst + hd * 32;
    float s1 = 0.f, s2 = 0.f;
#pragma unroll
    for (int i = 0; i < 32; i += 8) {
        uint4 hv = *(const uint4*)(hp + i);
        unsigned int u[4] = {hv.x, hv.y, hv.z, hv.w};
#pragma unroll
        for (int p = 0; p < 4; p++) {
            float f0 = __uint_as_float(u[p] << 16);
            float f1 = __uint_as_float(u[p] & 0xffff0000u);
            float av0 = as[i + 2 * p], av1 = as[i + 2 * p + 1];
            float dv0 = ad[i + 2 * p], dv1 = ad[i + 2 * p + 1];
            s1 += f0 * av0 + f1 * av1;
            s2 += f0 * dv0 + f1 * dv1;
        }
    }
    als[t] = s1; ald[t] = s2;
}

// ============================ CSR build (once) ===============================
__global__ void hist_kernel(const int* __restrict__ ei, int E, int N, int* __restrict__ deg)
{
    int t = blockIdx.x * blockDim.x + threadIdx.x;
    if (t >= E + N) return;
    int d = (t < E) ? ei[E + t] : (t - E);   // self loops appended
    atomicAdd(&deg[d], 1);
}

__global__ void scan1(const int* __restrict__ deg, int* __restrict__ rp,
                      int* __restrict__ bsum, int N)
{
    __shared__ int sh[256];
    int t = threadIdx.x;
    int i0 = blockIdx.x * 1024 + t * 4;
    int v[4];
#pragma unroll
    for (int j = 0; j < 4; j++) v[j] = (i0 + j < N) ? deg[i0 + j] : 0;
    int tot = v[0] + v[1] + v[2] + v[3];
    sh[t] = tot;
    __syncthreads();
    for (int off = 1; off < 256; off <<= 1) {
        int xv = (t >= off) ? sh[t - off] : 0;
        __syncthreads();
        sh[t] += xv;
        __syncthreads();
    }
    int run = sh[t] - tot;
    if (t == 255) bsum[blockIdx.x] = sh[255];
#pragma unroll
    for (int j = 0; j < 4; j++) {
        if (i0 + j < N) rp[i0 + j] = run;
        run += v[j];
    }
}

__global__ void scan2(int* __restrict__ bsum, int nb)
{
    if (threadIdx.x == 0 && blockIdx.x == 0) {
        int run = 0;
        for (int i = 0; i < nb; i++) { int v = bsum[i]; bsum[i] = run; run += v; }
    }
}

__global__ void scan3(int* __restrict__ rp, int* __restrict__ cur,
                      const int* __restrict__ bsum, int N, int Etot)
{
    int t = blockIdx.x * blockDim.x + threadIdx.x;
    if (t < N) {
        int v = rp[t] + bsum[t >> 10];
        rp[t] = v;
        cur[t] = v;
    } else if (t == N) {
        rp[N] = Etot;
    }
}

__global__ void scatter_kernel(const int* __restrict__ ei, int E, int N,
                               int* __restrict__ cur, int* __restrict__ col)
{
    int t = blockIdx.x * blockDim.x + threadIdx.x;
    if (t >= E + N) return;
    int s, d;
    if (t < E) { s = ei[t]; d = ei[E + t]; } else { s = t - E; d = t - E; }
    int p = atomicAdd(&cur[d], 1);
    col[p] = s;
}

// ============================ aggregation ====================================
// One wave per dst. h bf16 [N,128]; lane owns channels {2*lane, 2*lane+1}
// (head hB = lane>>4) -> ONE dword gather per edge per lane (256B/edge/wave).
// Softmax stats via shuffle butterfly (16 edge-lanes x 4 head-lanes).
// xio holds relu(y)+gb fp32; add aggregate + layer relu in place.
__global__ __launch_bounds__(256) void agg_kernel(
    const unsigned short* __restrict__ h, const float* __restrict__ als,
    const float* __restrict__ ald, const int* __restrict__ rp,
    const int* __restrict__ col, float* __restrict__ xio, int N)
{
    int wid  = (blockIdx.x * blockDim.x + threadIdx.x) >> 6;
    int lane = threadIdx.x & 63;
    if (wid >= N) return;
    int beg = rp[wid], end = rp[wid + 1];
    int deg = end - beg;

    // phase A: per-head max + sum-exp. lane -> (edge j = lane>>2, head = lane&3)
    int hA = lane & 3;
    float adA = ald[wid * 4 + hA];
    float mx = -1e30f;
    for (int j = lane >> 2; j < deg; j += 16) {
        int s = col[beg + j];
        float e = als[s * 4 + hA] + adA;
        e = e > 0.f ? e : NEG_SLOPE * e;
        mx = fmaxf(mx, e);
    }
#pragma unroll
    for (int off = 4; off < 64; off <<= 1) mx = fmaxf(mx, __shfl_xor(mx, off));
    float ss = 0.f;
    for (int j = lane >> 2; j < deg; j += 16) {
        int s = col[beg + j];
        float e = als[s * 4 + hA] + adA;
        e = e > 0.f ? e : NEG_SLOPE * e;
        ss += __expf(e - mx);
    }
#pragma unroll
    for (int off = 4; off < 64; off <<= 1) ss += __shfl_xor(ss, off);
    float inv = 1.0f / ss;

    // phase B: lane's head hB = lane>>4 (stats live at lane hB, since lane&3==hB there)
    int hB = lane >> 4;
    float m_h  = __shfl(mx, hB);
    float i_h  = __shfl(inv, hB);
    float ad_h = __shfl(adA, hB);
    const unsigned short* hbase = h + 2 * lane;
    float acc0 = 0.f, acc1 = 0.f;
    for (int j = beg; j < end; j++) {
        int s = col[j];
        float e = als[s * 4 + hB] + ad_h;
        e = e > 0.f ? e : NEG_SLOPE * e;
        float wgt = __expf(e - m_h) * i_h;
        unsigned int hv = *(const unsigned int*)(hbase + (size_t)s * HD);
        acc0 += wgt * __uint_as_float(hv << 16);
        acc1 += wgt * __uint_as_float(hv & 0xffff0000u);
    }
    float2* xp = (float2*)(xio + (size_t)wid * HD + 2 * lane);
    float2 xv = *xp;
    float v0 = acc0 + xv.x;
    float v1 = acc1 + xv.y;
    xv.x = v0 > 0.f ? v0 : 0.f;
    xv.y = v1 > 0.f ? v1 : 0.f;
    *xp = xv;
}

// ============================ classifier =====================================
__global__ __launch_bounds__(256) void cls_kernel(
    const float* __restrict__ x, const float* __restrict__ w,
    const float* __restrict__ b, float* __restrict__ out, int N)
{
    int wid  = (blockIdx.x * blockDim.x + threadIdx.x) >> 6;
    int lane = threadIdx.x & 63;
    if (wid >= N) return;
    float x0 = x[(size_t)wid * HD + lane];
    float x1 = x[(size_t)wid * HD + 64 + lane];
    float acc[10];
#pragma unroll
    for (int o = 0; o < 10; o++)
        acc[o] = x0 * w[lane * 10 + o] + x1 * w[(lane + 64) * 10 + o];
#pragma unroll
    for (int o = 0; o < 10; o++) {
        float v = acc[o];
#pragma unroll
        for (int off = 1; off < 64; off <<= 1) v += __shfl_xor(v, off);
        acc[o] = v;
    }
    float v = 0.f;
#pragma unroll
    for (int o = 0; o < 10; o++) if (lane == o) v = acc[o];
    if (lane < 10) out[(size_t)wid * 10 + lane] = v + b[lane];
}

// =============================================================================
extern "C" void kernel_launch(void* const* d_in, const int* in_sizes, int n_in,
                              void* d_out, int out_size, void* d_ws, size_t ws_size,
                              hipStream_t stream)
{
    const float* x0 = (const float*)d_in[0];
    const int*   ei = (const int*)d_in[1];
    const int N = in_sizes[0] / 512;
    const int E = in_sizes[1] / 2;
    const int Etot = E + N;

    const float *gw[3], *gas[3], *gad[3], *gbp[3], *fw[3], *fbp[3], *fgp[3], *fbt[3];
    for (int l = 0; l < 3; l++) {
        int b = 3 + 8 * l;
        gw[l]  = (const float*)d_in[b + 0];
        gas[l] = (const float*)d_in[b + 1];
        gad[l] = (const float*)d_in[b + 2];
        gbp[l] = (const float*)d_in[b + 3];
        fw[l]  = (const float*)d_in[b + 4];
        fbp[l] = (const float*)d_in[b + 5];
        fgp[l] = (const float*)d_in[b + 6];
        fbt[l] = (const float*)d_in[b + 7];
    }
    const float* cw = (const float*)d_in[27];
    const float* cb = (const float*)d_in[28];

    char* p = (char*)d_ws;
    auto carve = [&](size_t bytes) -> char* {
        char* r = p; p += (bytes + 255) & ~(size_t)255; return r;
    };
    float* xA   = (float*)carve((size_t)N * HD * 4);
    float* xB   = (float*)carve((size_t)N * HD * 4);
    unsigned short* hbuf = (unsigned short*)carve((size_t)N * HD * 2);   // bf16 h
    float* als  = (float*)carve((size_t)N * 4 * 4);
    float* ald  = (float*)carve((size_t)N * 4 * 4);
    int* rp   = (int*)carve((size_t)(N + 1) * 4);
    int* deg  = (int*)carve((size_t)N * 4);
    int* cur  = (int*)carve((size_t)N * 4);
    int* bsum = (int*)carve(4096);
    int* col  = (int*)carve((size_t)Etot * 4);
    unsigned short* gwT[3]; unsigned short* fwT[3];
    for (int l = 0; l < 3; l++) {
        int K = (l == 0) ? 512 : HD;
        gwT[l] = (unsigned short*)carve((size_t)128 * K * 2);
        fwT[l] = (unsigned short*)carve((size_t)128 * K * 2);
    }

    // ---- weight cast+transpose (tiny) ----
    for (int l = 0; l < 3; l++) {
        int K = (l == 0) ? 512 : HD;
        int nt = K * 128;
        prep_w<<<(nt + 255) / 256, 256, 0, stream>>>(gw[l], gwT[l], K);
        prep_w<<<(nt + 255) / 256, 256, 0, stream>>>(fw[l], fwT[l], K);
    }

    // ---- CSR by dst ----
    hipMemsetAsync(deg, 0, (size_t)N * 4, stream);
    hist_kernel<<<(Etot + 255) / 256, 256, 0, stream>>>(ei, E, N, deg);
    int nb = (N + 1023) / 1024;
    scan1<<<nb, 256, 0, stream>>>(deg, rp, bsum, N);
    scan2<<<1, 64, 0, stream>>>(bsum, nb);
    scan3<<<(N + 256) / 256, 256, 0, stream>>>(rp, cur, bsum, N, Etot);
    scatter_kernel<<<(Etot + 255) / 256, 256, 0, stream>>>(ei, E, N, cur, col);

    // ---- 3 message-passing layers ----
    for (int l = 0; l < 3; l++) {
        const float* xin = (l == 0) ? x0 : ((l == 1) ? xA : xB);
        float* xout = (l == 1) ? xB : xA;
        int K = (l == 0) ? 512 : HD;
        int mblocks = (N + 63) / 64;
        gemm_mfma<<<mblocks, 256, 0, stream>>>(xin, gwT[l], hbuf, N, K, 0,
                                               nullptr, nullptr, nullptr, nullptr);
        al_kernel<<<(N * 4 + 255) / 256, 256, 0, stream>>>(hbuf, gas[l], gad[l], als, ald, N);
        gemm_mfma<<<mblocks, 256, 0, stream>>>(xin, fwT[l], xout, N, K, 1,
                                               fbp[l], fgp[l], fbt[l], gbp[l]);
        agg_kernel<<<(N + 3) / 4, 256, 0, stream>>>(hbuf, als, ald, rp, col, xout, N);
    }

    // ---- classifier ----
    cls_kernel<<<(N + 3) / 4, 256, 0, stream>>>(xA, cw, cb, (float*)d_out, N);
}

// Round 4
// 865.346 us; speedup vs baseline: 1.5269x; 1.1734x over previous
//
#include <hip/hip_runtime.h>
#include <cstdint>
#include <cstddef>

#define HD 128
#define NEG_SLOPE 0.2f
#define BN_EPS 1e-5f

typedef __bf16 bf16x8 __attribute__((ext_vector_type(8)));
typedef float  f32x4  __attribute__((ext_vector_type(4)));

__device__ __forceinline__ unsigned short f2b(float f) {   // fp32 -> bf16 RNE
    unsigned int u = __float_as_uint(f);
    u = (u + 0x7fffu + ((u >> 16) & 1u)) >> 16;
    return (unsigned short)u;
}
__device__ __forceinline__ unsigned int pack2(float lo, float hi) {
    return (unsigned int)f2b(lo) | ((unsigned int)f2b(hi) << 16);
}

// =============================================================================
// Weight prep: gw,fw fp32 [K][128] -> Wt bf16 [256][K]  (rows 0..127 = gw cols,
// rows 128..255 = fw cols; cast + transpose, tiny)
// =============================================================================
__global__ void prep_w2(const float* __restrict__ gw, const float* __restrict__ fw,
                        unsigned short* __restrict__ Wt, int K)
{
    int t = blockIdx.x * 256 + threadIdx.x;
    if (t >= K * 256) return;
    int k = t >> 8, c = t & 255;
    float v = (c < 128) ? gw[(size_t)k * 128 + c] : fw[(size_t)k * 128 + (c - 128)];
    Wt[(size_t)c * K + k] = f2b(v);
}

// =============================================================================
// Fused dual GEMM: [h | y] [M,256] = X[M,K](fp32->bf16 stage) @ Wt[256,K]
// Tile 64(M) x 256(N), BK=32, 256 thr = 4 waves, col-split: wave w owns cols
// 64w..64w+63 (4 col-tiles) x all 4 row-tiles -> 16 MFMA/K-step,
// 4 A-frag + 4 B-frag LDS reads. Waves 0,1 -> h (bf16); waves 2,3 -> y =
// relu((acc+fb)*g+fbeta)+gb (fp32). Frag layouts (verified R3):
// A[m=lane&15][k=q*8+j], B[k=q*8+j][n=lane&15], D col=lane&15 row=q*4+reg.
// =============================================================================
__global__ __launch_bounds__(256) void gemm_dual(
    const float* __restrict__ X, const unsigned short* __restrict__ Wt,
    unsigned short* __restrict__ hb, float* __restrict__ yb, int M, int K,
    const float* __restrict__ fb, const float* __restrict__ fg,
    const float* __restrict__ fbeta, const float* __restrict__ gb)
{
    __shared__ __align__(16) char smem[64 * 80 + 256 * 80];   // pad 32->40 bf16
    char* Asb = smem;
    char* Bsb = smem + 64 * 80;

    const int tid  = threadIdx.x;
    const int row0 = blockIdx.x * 64;
    const int w    = tid >> 6;
    const int lane = tid & 63;
    const int m    = lane & 15;
    const int q    = lane >> 4;

    const int ar = tid >> 2;             // A: row 0..63
    const int ak = (tid & 3) * 8;        //    k offset (8 floats)
    // B: one thread per output-col row (0..255), 32 bf16 each

    int arow = row0 + ar; if (arow >= M) arow = M - 1;

    f32x4 acc[4][4];
#pragma unroll
    for (int rt = 0; rt < 4; rt++)
#pragma unroll
        for (int ci = 0; ci < 4; ci++) acc[rt][ci] = (f32x4){0.f, 0.f, 0.f, 0.f};

    const int aoff_w = ar * 80 + ak * 2;
    const int boff_w = tid * 80;

    for (int ks = 0; ks < K; ks += 32) {
        const float* xr = X + (size_t)arow * K + ks + ak;
        float4 a0 = *(const float4*)xr;
        float4 a1 = *(const float4*)(xr + 4);
        const unsigned short* wr = Wt + (size_t)tid * K + ks;
        uint4 b0 = *(const uint4*)wr;
        uint4 b1 = *(const uint4*)(wr + 8);
        uint4 b2 = *(const uint4*)(wr + 16);
        uint4 b3 = *(const uint4*)(wr + 24);
        __syncthreads();
        uint4 ap;
        ap.x = pack2(a0.x, a0.y); ap.y = pack2(a0.z, a0.w);
        ap.z = pack2(a1.x, a1.y); ap.w = pack2(a1.z, a1.w);
        *(uint4*)(Asb + aoff_w) = ap;
        *(uint4*)(Bsb + boff_w)      = b0;
        *(uint4*)(Bsb + boff_w + 16) = b1;
        *(uint4*)(Bsb + boff_w + 32) = b2;
        *(uint4*)(Bsb + boff_w + 48) = b3;
        __syncthreads();
        bf16x8 af[4], bfr[4];
#pragma unroll
        for (int rt = 0; rt < 4; rt++)
            af[rt] = *(const bf16x8*)(Asb + (rt * 16 + m) * 80 + q * 16);
#pragma unroll
        for (int ci = 0; ci < 4; ci++)
            bfr[ci] = *(const bf16x8*)(Bsb + (64 * w + ci * 16 + m) * 80 + q * 16);
#pragma unroll
        for (int rt = 0; rt < 4; rt++)
#pragma unroll
            for (int ci = 0; ci < 4; ci++)
                acc[rt][ci] = __builtin_amdgcn_mfma_f32_16x16x32_bf16(af[rt], bfr[ci], acc[rt][ci], 0, 0, 0);
    }

    // epilogue: D[row = row0+rt*16+q*4+r][gcol = 64w+ci*16+m]
    if (w < 2) {               // h columns 0..127, bf16
#pragma unroll
        for (int ci = 0; ci < 4; ci++) {
            int col = 64 * w + ci * 16 + m;
#pragma unroll
            for (int rt = 0; rt < 4; rt++)
#pragma unroll
                for (int r = 0; r < 4; r++) {
                    int row = row0 + rt * 16 + q * 4 + r;
                    if (row < M) hb[(size_t)row * HD + col] = f2b(acc[rt][ci][r]);
                }
        }
    } else {                   // y columns 0..127, fp32 with BN+relu+gb
        const float inv_bn = 1.0f / sqrtf(1.0f + BN_EPS);
#pragma unroll
        for (int ci = 0; ci < 4; ci++) {
            int col = 64 * (w - 2) + ci * 16 + m;
            float g  = fg[col] * inv_bn;
            float bb = fb[col];
            float bt = fbeta[col];
            float gv = gb[col];
#pragma unroll
            for (int rt = 0; rt < 4; rt++)
#pragma unroll
                for (int r = 0; r < 4; r++) {
                    int row = row0 + rt * 16 + q * 4 + r;
                    if (row < M) {
                        float y = (acc[rt][ci][r] + bb) * g + bt;
                        y = y > 0.f ? y : 0.f;           // feature_transform relu
                        yb[(size_t)row * HD + col] = y + gv;
                    }
                }
        }
    }
}

// ============================ attention logits ===============================
__global__ void al_kernel(const unsigned short* __restrict__ h,
                          const float* __restrict__ a_src, const float* __restrict__ a_dst,
                          float* __restrict__ als, float* __restrict__ ald, int N)
{
    int t = blockIdx.x * blockDim.x + threadIdx.x;
    if (t >= N * 4) return;
    int n = t >> 2, hd = t & 3;
    const unsigned short* hp = h + (size_t)n * HD + hd * 32;
    const float* as = a_src + hd * 32;
    const float* ad = a_dst + hd * 32;
    float s1 = 0.f, s2 = 0.f;
#pragma unroll
    for (int i = 0; i < 32; i += 8) {
        uint4 hv = *(const uint4*)(hp + i);
        unsigned int u[4] = {hv.x, hv.y, hv.z, hv.w};
#pragma unroll
        for (int p = 0; p < 4; p++) {
            float f0 = __uint_as_float(u[p] << 16);
            float f1 = __uint_as_float(u[p] & 0xffff0000u);
            s1 += f0 * as[i + 2 * p] + f1 * as[i + 2 * p + 1];
            s2 += f0 * ad[i + 2 * p] + f1 * ad[i + 2 * p + 1];
        }
    }
    als[t] = s1; ald[t] = s2;
}

// ============================ CSR build (once) ===============================
__global__ void hist_kernel(const int* __restrict__ ei, int E, int N, int* __restrict__ deg)
{
    int t = blockIdx.x * blockDim.x + threadIdx.x;
    if (t >= E + N) return;
    int d = (t < E) ? ei[E + t] : (t - E);
    atomicAdd(&deg[d], 1);
}

__global__ void scan1(const int* __restrict__ deg, int* __restrict__ rp,
                      int* __restrict__ bsum, int N)
{
    __shared__ int sh[256];
    int t = threadIdx.x;
    int i0 = blockIdx.x * 1024 + t * 4;
    int v[4];
#pragma unroll
    for (int j = 0; j < 4; j++) v[j] = (i0 + j < N) ? deg[i0 + j] : 0;
    int tot = v[0] + v[1] + v[2] + v[3];
    sh[t] = tot;
    __syncthreads();
    for (int off = 1; off < 256; off <<= 1) {
        int xv = (t >= off) ? sh[t - off] : 0;
        __syncthreads();
        sh[t] += xv;
        __syncthreads();
    }
    int run = sh[t] - tot;
    if (t == 255) bsum[blockIdx.x] = sh[255];
#pragma unroll
    for (int j = 0; j < 4; j++) {
        if (i0 + j < N) rp[i0 + j] = run;
        run += v[j];
    }
}

__global__ void scan2(int* __restrict__ bsum, int nb)
{
    if (threadIdx.x == 0 && blockIdx.x == 0) {
        int run = 0;
        for (int i = 0; i < nb; i++) { int v = bsum[i]; bsum[i] = run; run += v; }
    }
}

__global__ void scan3(int* __restrict__ rp, int* __restrict__ cur,
                      const int* __restrict__ bsum, int N, int Etot)
{
    int t = blockIdx.x * blockDim.x + threadIdx.x;
    if (t < N) {
        int v = rp[t] + bsum[t >> 10];
        rp[t] = v;
        cur[t] = v;
    } else if (t == N) {
        rp[N] = Etot;
    }
}

__global__ void scatter_kernel(const int* __restrict__ ei, int E, int N,
                               int* __restrict__ cur, int* __restrict__ col)
{
    int t = blockIdx.x * blockDim.x + threadIdx.x;
    if (t >= E + N) return;
    int s, d;
    if (t < E) { s = ei[t]; d = ei[E + t]; } else { s = t - E; d = t - E; }
    int p = atomicAdd(&cur[d], 1);
    col[p] = s;
}

// ============================ aggregation ====================================
// One wave per dst. Phase A: (16 edge-lanes x 4 head-lanes) softmax stats.
// Phase B: 4 edge-slots in flight; lane = (g=lane>>4, c=lane&15), lane owns
// channels c*8..c*8+7 (head c>>2) of edge-slot g -> one dwordx4 gather per
// edge per lane; cross-slot combine via shfl_xor(16|32).
__global__ __launch_bounds__(256) void agg_kernel(
    const unsigned short* __restrict__ h, const float* __restrict__ als,
    const float* __restrict__ ald, const int* __restrict__ rp,
    const int* __restrict__ col, float* __restrict__ xio, int N)
{
    int wid  = (blockIdx.x * blockDim.x + threadIdx.x) >> 6;
    int lane = threadIdx.x & 63;
    if (wid >= N) return;
    int beg = rp[wid], end = rp[wid + 1];
    int deg = end - beg;

    // phase A
    int hA = lane & 3;
    float adA = ald[wid * 4 + hA];
    float mx = -1e30f;
    for (int j = lane >> 2; j < deg; j += 16) {
        int s = col[beg + j];
        float e = als[s * 4 + hA] + adA;
        e = e > 0.f ? e : NEG_SLOPE * e;
        mx = fmaxf(mx, e);
    }
#pragma unroll
    for (int off = 4; off < 64; off <<= 1) mx = fmaxf(mx, __shfl_xor(mx, off));
    float ss = 0.f;
    for (int j = lane >> 2; j < deg; j += 16) {
        int s = col[beg + j];
        float e = als[s * 4 + hA] + adA;
        e = e > 0.f ? e : NEG_SLOPE * e;
        ss += __expf(e - mx);
    }
#pragma unroll
    for (int off = 4; off < 64; off <<= 1) ss += __shfl_xor(ss, off);
    float inv = 1.0f / ss;

    // phase B
    int g = lane >> 4, c = lane & 15;
    int hB = c >> 2;
    float m_h  = __shfl(mx, hB);     // lanes 0..3 hold heads 0..3 after butterfly
    float i_h  = __shfl(inv, hB);
    float ad_h = __shfl(adA, hB);
    float acc[8];
#pragma unroll
    for (int p = 0; p < 8; p++) acc[p] = 0.f;
    const unsigned short* hbase = h + c * 8;
    for (int j = beg + g; j < end; j += 4) {
        int s = col[j];
        float e = als[s * 4 + hB] + ad_h;
        e = e > 0.f ? e : NEG_SLOPE * e;
        float wgt = __expf(e - m_h) * i_h;
        uint4 hv = *(const uint4*)(hbase + (size_t)s * HD);
        unsigned int uu[4] = {hv.x, hv.y, hv.z, hv.w};
#pragma unroll
        for (int p = 0; p < 4; p++) {
            acc[2 * p]     += wgt * __uint_as_float(uu[p] << 16);
            acc[2 * p + 1] += wgt * __uint_as_float(uu[p] & 0xffff0000u);
        }
    }
#pragma unroll
    for (int p = 0; p < 8; p++) {
        acc[p] += __shfl_xor(acc[p], 16);
        acc[p] += __shfl_xor(acc[p], 32);
    }
    if (g == 0) {
        float* xp = xio + (size_t)wid * HD + c * 8;
        float4 x0 = *(float4*)xp, x1 = *(float4*)(xp + 4);
        float o[8] = {acc[0] + x0.x, acc[1] + x0.y, acc[2] + x0.z, acc[3] + x0.w,
                      acc[4] + x1.x, acc[5] + x1.y, acc[6] + x1.z, acc[7] + x1.w};
#pragma unroll
        for (int p = 0; p < 8; p++) o[p] = o[p] > 0.f ? o[p] : 0.f;
        *(float4*)xp       = (float4){o[0], o[1], o[2], o[3]};
        *(float4*)(xp + 4) = (float4){o[4], o[5], o[6], o[7]};
    }
}

// ============================ classifier =====================================
__global__ __launch_bounds__(256) void cls_kernel(
    const float* __restrict__ x, const float* __restrict__ w,
    const float* __restrict__ b, float* __restrict__ out, int N)
{
    int wid  = (blockIdx.x * blockDim.x + threadIdx.x) >> 6;
    int lane = threadIdx.x & 63;
    if (wid >= N) return;
    float x0 = x[(size_t)wid * HD + lane];
    float x1 = x[(size_t)wid * HD + 64 + lane];
    float acc[10];
#pragma unroll
    for (int o = 0; o < 10; o++)
        acc[o] = x0 * w[lane * 10 + o] + x1 * w[(lane + 64) * 10 + o];
#pragma unroll
    for (int o = 0; o < 10; o++) {
        float v = acc[o];
#pragma unroll
        for (int off = 1; off < 64; off <<= 1) v += __shfl_xor(v, off);
        acc[o] = v;
    }
    float v = 0.f;
#pragma unroll
    for (int o = 0; o < 10; o++) if (lane == o) v = acc[o];
    if (lane < 10) out[(size_t)wid * 10 + lane] = v + b[lane];
}

// =============================================================================
extern "C" void kernel_launch(void* const* d_in, const int* in_sizes, int n_in,
                              void* d_out, int out_size, void* d_ws, size_t ws_size,
                              hipStream_t stream)
{
    const float* x0 = (const float*)d_in[0];
    const int*   ei = (const int*)d_in[1];
    const int N = in_sizes[0] / 512;
    const int E = in_sizes[1] / 2;
    const int Etot = E + N;

    const float *gw[3], *gas[3], *gad[3], *gbp[3], *fw[3], *fbp[3], *fgp[3], *fbt[3];
    for (int l = 0; l < 3; l++) {
        int b = 3 + 8 * l;
        gw[l]  = (const float*)d_in[b + 0];
        gas[l] = (const float*)d_in[b + 1];
        gad[l] = (const float*)d_in[b + 2];
        gbp[l] = (const float*)d_in[b + 3];
        fw[l]  = (const float*)d_in[b + 4];
        fbp[l] = (const float*)d_in[b + 5];
        fgp[l] = (const float*)d_in[b + 6];
        fbt[l] = (const float*)d_in[b + 7];
    }
    const float* cw = (const float*)d_in[27];
    const float* cb = (const float*)d_in[28];

    char* p = (char*)d_ws;
    auto carve = [&](size_t bytes) -> char* {
        char* r = p; p += (bytes + 255) & ~(size_t)255; return r;
    };
    float* xA   = (float*)carve((size_t)N * HD * 4);
    float* xB   = (float*)carve((size_t)N * HD * 4);
    unsigned short* hbuf = (unsigned short*)carve((size_t)N * HD * 2);   // bf16 h
    float* als  = (float*)carve((size_t)N * 4 * 4);
    float* ald  = (float*)carve((size_t)N * 4 * 4);
    int* rp   = (int*)carve((size_t)(N + 1) * 4);
    int* deg  = (int*)carve((size_t)N * 4);
    int* cur  = (int*)carve((size_t)N * 4);
    int* bsum = (int*)carve(4096);
    int* col  = (int*)carve((size_t)Etot * 4);
    unsigned short* wT[3];
    for (int l = 0; l < 3; l++) {
        int K = (l == 0) ? 512 : HD;
        wT[l] = (unsigned short*)carve((size_t)256 * K * 2);
    }

    // ---- weight cast+transpose+concat (tiny) ----
    for (int l = 0; l < 3; l++) {
        int K = (l == 0) ? 512 : HD;
        int nt = K * 256;
        prep_w2<<<(nt + 255) / 256, 256, 0, stream>>>(gw[l], fw[l], wT[l], K);
    }

    // ---- CSR by dst ----
    hipMemsetAsync(deg, 0, (size_t)N * 4, stream);
    hist_kernel<<<(Etot + 255) / 256, 256, 0, stream>>>(ei, E, N, deg);
    int nb = (N + 1023) / 1024;
    scan1<<<nb, 256, 0, stream>>>(deg, rp, bsum, N);
    scan2<<<1, 64, 0, stream>>>(bsum, nb);
    scan3<<<(N + 256) / 256, 256, 0, stream>>>(rp, cur, bsum, N, Etot);
    scatter_kernel<<<(Etot + 255) / 256, 256, 0, stream>>>(ei, E, N, cur, col);

    // ---- 3 message-passing layers ----
    for (int l = 0; l < 3; l++) {
        const float* xin = (l == 0) ? x0 : ((l == 1) ? xA : xB);
        float* xout = (l == 1) ? xB : xA;
        int K = (l == 0) ? 512 : HD;
        int mblocks = (N + 63) / 64;
        gemm_dual<<<mblocks, 256, 0, stream>>>(xin, wT[l], hbuf, xout, N, K,
                                               fbp[l], fgp[l], fbt[l], gbp[l]);
        al_kernel<<<(N * 4 + 255) / 256, 256, 0, stream>>>(hbuf, gas[l], gad[l], als, ald, N);
        agg_kernel<<<(N + 3) / 4, 256, 0, stream>>>(hbuf, als, ald, rp, col, xout, N);
    }

    // ---- classifier ----
    cls_kernel<<<(N + 3) / 4, 256, 0, stream>>>(xA, cw, cb, (float*)d_out, N);
}

// Round 5
// 790.459 us; speedup vs baseline: 1.6715x; 1.0947x over previous
//
#include <hip/hip_runtime.h>
#include <cstdint>
#include <cstddef>

#define HD 128
#define NEG_SLOPE 0.2f
#define BN_EPS 1e-5f

typedef __bf16 bf16x8 __attribute__((ext_vector_type(8)));
typedef float  f32x4  __attribute__((ext_vector_type(4)));

__device__ __forceinline__ unsigned short f2b(float f) {   // fp32 -> bf16 RNE
    unsigned int u = __float_as_uint(f);
    u = (u + 0x7fffu + ((u >> 16) & 1u)) >> 16;
    return (unsigned short)u;
}
__device__ __forceinline__ unsigned int pack2(float lo, float hi) {
    return (unsigned int)f2b(lo) | ((unsigned int)f2b(hi) << 16);
}

// =============================================================================
// Weight prep: gw,fw fp32 [K][128] -> Wt bf16 [256][K]  (cols 0..127 = gw,
// 128..255 = fw; cast + transpose, tiny)
// =============================================================================
__global__ void prep_w2(const float* __restrict__ gw, const float* __restrict__ fw,
                        unsigned short* __restrict__ Wt, int K)
{
    int t = blockIdx.x * 256 + threadIdx.x;
    if (t >= K * 256) return;
    int k = t >> 8, c = t & 255;
    float v = (c < 128) ? gw[(size_t)k * 128 + c] : fw[(size_t)k * 128 + (c - 128)];
    Wt[(size_t)c * K + k] = f2b(v);
}

// =============================================================================
// Fused dual GEMM, software-pipelined: [h | y][M,256] = X[M,K] @ Wt[256,K]
// Tile 128(M) x 256(N), BK=32, 512 thr = 8 waves (2M x 4N); wave = 64x64 slab
// = 4x4 16x16 tiles -> 16 MFMA + 8 ds_read_b128 per K-step.
// Register double-buffer: tile k+1 global loads issued BEFORE the MFMA block
// so latency drains behind compute (fix for R4's MfmaUtil=6%).
// LDS rows padded to 80B (2-way bank aliasing only = free).
// h cols (wn<2) -> bf16; y cols (wn>=2) -> fp32 relu((acc+fb)*g+fbeta)+gb.
// Frag layouts (verified R3/R4): A[m=lane&15][k=q*8+j], B[k=q*8+j][n=lane&15],
// D col=lane&15, row=q*4+reg.
// =============================================================================
__global__ __launch_bounds__(512, 4) void gemm_dual(
    const float* __restrict__ X, const unsigned short* __restrict__ Wt,
    unsigned short* __restrict__ hb, float* __restrict__ yb, int M, int K,
    const float* __restrict__ fb, const float* __restrict__ fg,
    const float* __restrict__ fbeta, const float* __restrict__ gb)
{
    __shared__ __align__(16) char smem[128 * 80 + 256 * 80];
    char* Asb = smem;               // 128 rows x 80B (32 bf16 + pad)
    char* Bsb = smem + 128 * 80;    // 256 out-col rows x 80B

    const int tid  = threadIdx.x;
    const int row0 = blockIdx.x * 128;
    const int w    = tid >> 6, lane = tid & 63;
    const int wm   = w & 1,  wn = w >> 1;
    const int m    = lane & 15, q = lane >> 4;

    const int ra = tid >> 2, ka = (tid & 3) * 8;    // A stage: 8 elems/thread
    const int rb = tid >> 1, kb = (tid & 1) * 16;   // B stage: 16 elems/thread

    int arow = row0 + ra; if (arow >= M) arow = M - 1;

    f32x4 acc[4][4];
#pragma unroll
    for (int rt = 0; rt < 4; rt++)
#pragma unroll
        for (int ct = 0; ct < 4; ct++) acc[rt][ct] = (f32x4){0.f, 0.f, 0.f, 0.f};

    const int aw = ra * 80 + ka * 2;
    const int bw = rb * 80 + kb * 2;

    // prologue: prefetch tile 0
    float4 pa0, pa1;
    uint4  pb0, pb1;
    {
        const float* xr = X + (size_t)arow * K + ka;
        pa0 = *(const float4*)xr; pa1 = *(const float4*)(xr + 4);
        const unsigned short* wr = Wt + (size_t)rb * K + kb;
        pb0 = *(const uint4*)wr; pb1 = *(const uint4*)(wr + 8);
    }

    for (int ks = 0; ks < K; ks += 32) {
        __syncthreads();
        uint4 av;
        av.x = pack2(pa0.x, pa0.y); av.y = pack2(pa0.z, pa0.w);
        av.z = pack2(pa1.x, pa1.y); av.w = pack2(pa1.z, pa1.w);
        *(uint4*)(Asb + aw) = av;
        *(uint4*)(Bsb + bw)      = pb0;
        *(uint4*)(Bsb + bw + 16) = pb1;
        __syncthreads();

        // prefetch tile ks+32 (in flight during MFMA below)
        int kn = ks + 32;
        if (kn < K) {
            const float* xr = X + (size_t)arow * K + kn + ka;
            pa0 = *(const float4*)xr; pa1 = *(const float4*)(xr + 4);
            const unsigned short* wr = Wt + (size_t)rb * K + kn + kb;
            pb0 = *(const uint4*)wr; pb1 = *(const uint4*)(wr + 8);
        }

        bf16x8 af[4], bfr[4];
#pragma unroll
        for (int rt = 0; rt < 4; rt++)
            af[rt] = *(const bf16x8*)(Asb + (64 * wm + rt * 16 + m) * 80 + q * 16);
#pragma unroll
        for (int ct = 0; ct < 4; ct++)
            bfr[ct] = *(const bf16x8*)(Bsb + (64 * wn + ct * 16 + m) * 80 + q * 16);
#pragma unroll
        for (int rt = 0; rt < 4; rt++)
#pragma unroll
            for (int ct = 0; ct < 4; ct++)
                acc[rt][ct] = __builtin_amdgcn_mfma_f32_16x16x32_bf16(af[rt], bfr[ct], acc[rt][ct], 0, 0, 0);
    }

    // epilogue: D[row = row0+64*wm+rt*16+q*4+r][gcol = 64*wn+ct*16+m]
    if (wn < 2) {              // h half, bf16
#pragma unroll
        for (int ct = 0; ct < 4; ct++) {
            int col = 64 * wn + ct * 16 + m;
#pragma unroll
            for (int rt = 0; rt < 4; rt++)
#pragma unroll
                for (int r = 0; r < 4; r++) {
                    int row = row0 + 64 * wm + rt * 16 + q * 4 + r;
                    if (row < M) hb[(size_t)row * HD + col] = f2b(acc[rt][ct][r]);
                }
        }
    } else {                   // y half, fp32 with BN+relu+gb
        const float inv_bn = 1.0f / sqrtf(1.0f + BN_EPS);
#pragma unroll
        for (int ct = 0; ct < 4; ct++) {
            int col = 64 * (wn - 2) + ct * 16 + m;
            float g  = fg[col] * inv_bn;
            float bb = fb[col];
            float bt = fbeta[col];
            float gv = gb[col];
#pragma unroll
            for (int rt = 0; rt < 4; rt++)
#pragma unroll
                for (int r = 0; r < 4; r++) {
                    int row = row0 + 64 * wm + rt * 16 + q * 4 + r;
                    if (row < M) {
                        float y = (acc[rt][ct][r] + bb) * g + bt;
                        y = y > 0.f ? y : 0.f;       // feature_transform relu
                        yb[(size_t)row * HD + col] = y + gv;
                    }
                }
        }
    }
}

// ============================ attention logits ===============================
__global__ void al_kernel(const unsigned short* __restrict__ h,
                          const float* __restrict__ a_src, const float* __restrict__ a_dst,
                          float* __restrict__ als, float* __restrict__ ald, int N)
{
    int t = blockIdx.x * blockDim.x + threadIdx.x;
    if (t >= N * 4) return;
    int n = t >> 2, hd = t & 3;
    const unsigned short* hp = h + (size_t)n * HD + hd * 32;
    const float* as = a_src + hd * 32;
    const float* ad = a_dst + hd * 32;
    float s1 = 0.f, s2 = 0.f;
#pragma unroll
    for (int i = 0; i < 32; i += 8) {
        uint4 hv = *(const uint4*)(hp + i);
        unsigned int u[4] = {hv.x, hv.y, hv.z, hv.w};
#pragma unroll
        for (int p = 0; p < 4; p++) {
            float f0 = __uint_as_float(u[p] << 16);
            float f1 = __uint_as_float(u[p] & 0xffff0000u);
            s1 += f0 * as[i + 2 * p] + f1 * as[i + 2 * p + 1];
            s2 += f0 * ad[i + 2 * p] + f1 * ad[i + 2 * p + 1];
        }
    }
    als[t] = s1; ald[t] = s2;
}

// ============================ CSR build (once) ===============================
__global__ void hist_kernel(const int* __restrict__ ei, int E, int N, int* __restrict__ deg)
{
    int t = blockIdx.x * blockDim.x + threadIdx.x;
    if (t >= E + N) return;
    int d = (t < E) ? ei[E + t] : (t - E);
    atomicAdd(&deg[d], 1);
}

__global__ void scan1(const int* __restrict__ deg, int* __restrict__ rp,
                      int* __restrict__ bsum, int N)
{
    __shared__ int sh[256];
    int t = threadIdx.x;
    int i0 = blockIdx.x * 1024 + t * 4;
    int v[4];
#pragma unroll
    for (int j = 0; j < 4; j++) v[j] = (i0 + j < N) ? deg[i0 + j] : 0;
    int tot = v[0] + v[1] + v[2] + v[3];
    sh[t] = tot;
    __syncthreads();
    for (int off = 1; off < 256; off <<= 1) {
        int xv = (t >= off) ? sh[t - off] : 0;
        __syncthreads();
        sh[t] += xv;
        __syncthreads();
    }
    int run = sh[t] - tot;
    if (t == 255) bsum[blockIdx.x] = sh[255];
#pragma unroll
    for (int j = 0; j < 4; j++) {
        if (i0 + j < N) rp[i0 + j] = run;
        run += v[j];
    }
}

__global__ void scan2(int* __restrict__ bsum, int nb)
{
    if (threadIdx.x == 0 && blockIdx.x == 0) {
        int run = 0;
        for (int i = 0; i < nb; i++) { int v = bsum[i]; bsum[i] = run; run += v; }
    }
}

__global__ void scan3(int* __restrict__ rp, int* __restrict__ cur,
                      const int* __restrict__ bsum, int N, int Etot)
{
    int t = blockIdx.x * blockDim.x + threadIdx.x;
    if (t < N) {
        int v = rp[t] + bsum[t >> 10];
        rp[t] = v;
        cur[t] = v;
    } else if (t == N) {
        rp[N] = Etot;
    }
}

__global__ void scatter_kernel(const int* __restrict__ ei, int E, int N,
                               int* __restrict__ cur, int* __restrict__ col)
{
    int t = blockIdx.x * blockDim.x + threadIdx.x;
    if (t >= E + N) return;
    int s, d;
    if (t < E) { s = ei[t]; d = ei[E + t]; } else { s = t - E; d = t - E; }
    int p = atomicAdd(&cur[d], 1);
    col[p] = s;
}

// ============================ aggregation ====================================
// SINGLE-PASS per dst (no max-subtraction: logits ~N(0,sqrt2), |e|<~20, exp
// is fp32-safe; softmax value identical). One wave per dst; lane=(g=lane>>4
// edge-slot, c=lane&15 channel-group, head=c>>2). 4 edges in flight; each
// lane accumulates sum(exp*h[8ch]) AND sum(exp); combine slots via
// shfl_xor(16|32); normalize once at the end. xio fp32 RMW + layer relu.
__global__ __launch_bounds__(256) void agg_kernel(
    const unsigned short* __restrict__ h, const float* __restrict__ als,
    const float* __restrict__ ald, const int* __restrict__ rp,
    const int* __restrict__ col, float* __restrict__ xio, int N)
{
    int wid  = (blockIdx.x * blockDim.x + threadIdx.x) >> 6;
    int lane = threadIdx.x & 63;
    if (wid >= N) return;
    int beg = rp[wid], end = rp[wid + 1];

    int g = lane >> 4, c = lane & 15, hB = c >> 2;
    float ad_h = ald[wid * 4 + hB];
    float acc[8];
#pragma unroll
    for (int p = 0; p < 8; p++) acc[p] = 0.f;
    float wsum = 0.f;
    const unsigned short* hbase = h + c * 8;
    for (int j = beg + g; j < end; j += 4) {
        int s = col[j];
        float e = als[s * 4 + hB] + ad_h;
        e = e > 0.f ? e : NEG_SLOPE * e;
        float wgt = __expf(e);
        wsum += wgt;
        uint4 hv = *(const uint4*)(hbase + (size_t)s * HD);
        unsigned int uu[4] = {hv.x, hv.y, hv.z, hv.w};
#pragma unroll
        for (int p = 0; p < 4; p++) {
            acc[2 * p]     += wgt * __uint_as_float(uu[p] << 16);
            acc[2 * p + 1] += wgt * __uint_as_float(uu[p] & 0xffff0000u);
        }
    }
#pragma unroll
    for (int p = 0; p < 8; p++) {
        acc[p] += __shfl_xor(acc[p], 16);
        acc[p] += __shfl_xor(acc[p], 32);
    }
    wsum += __shfl_xor(wsum, 16);
    wsum += __shfl_xor(wsum, 32);
    if (g == 0) {
        float inv = 1.0f / wsum;
        float* xp = xio + (size_t)wid * HD + c * 8;
        float4 x0 = *(float4*)xp, x1 = *(float4*)(xp + 4);
        float o[8] = {acc[0] * inv + x0.x, acc[1] * inv + x0.y,
                      acc[2] * inv + x0.z, acc[3] * inv + x0.w,
                      acc[4] * inv + x1.x, acc[5] * inv + x1.y,
                      acc[6] * inv + x1.z, acc[7] * inv + x1.w};
#pragma unroll
        for (int p = 0; p < 8; p++) o[p] = o[p] > 0.f ? o[p] : 0.f;
        *(float4*)xp       = (float4){o[0], o[1], o[2], o[3]};
        *(float4*)(xp + 4) = (float4){o[4], o[5], o[6], o[7]};
    }
}

// ============================ classifier =====================================
__global__ __launch_bounds__(256) void cls_kernel(
    const float* __restrict__ x, const float* __restrict__ w,
    const float* __restrict__ b, float* __restrict__ out, int N)
{
    int wid  = (blockIdx.x * blockDim.x + threadIdx.x) >> 6;
    int lane = threadIdx.x & 63;
    if (wid >= N) return;
    float x0 = x[(size_t)wid * HD + lane];
    float x1 = x[(size_t)wid * HD + 64 + lane];
    float acc[10];
#pragma unroll
    for (int o = 0; o < 10; o++)
        acc[o] = x0 * w[lane * 10 + o] + x1 * w[(lane + 64) * 10 + o];
#pragma unroll
    for (int o = 0; o < 10; o++) {
        float v = acc[o];
#pragma unroll
        for (int off = 1; off < 64; off <<= 1) v += __shfl_xor(v, off);
        acc[o] = v;
    }
    float v = 0.f;
#pragma unroll
    for (int o = 0; o < 10; o++) if (lane == o) v = acc[o];
    if (lane < 10) out[(size_t)wid * 10 + lane] = v + b[lane];
}

// =============================================================================
extern "C" void kernel_launch(void* const* d_in, const int* in_sizes, int n_in,
                              void* d_out, int out_size, void* d_ws, size_t ws_size,
                              hipStream_t stream)
{
    const float* x0 = (const float*)d_in[0];
    const int*   ei = (const int*)d_in[1];
    const int N = in_sizes[0] / 512;
    const int E = in_sizes[1] / 2;
    const int Etot = E + N;

    const float *gw[3], *gas[3], *gad[3], *gbp[3], *fw[3], *fbp[3], *fgp[3], *fbt[3];
    for (int l = 0; l < 3; l++) {
        int b = 3 + 8 * l;
        gw[l]  = (const float*)d_in[b + 0];
        gas[l] = (const float*)d_in[b + 1];
        gad[l] = (const float*)d_in[b + 2];
        gbp[l] = (const float*)d_in[b + 3];
        fw[l]  = (const float*)d_in[b + 4];
        fbp[l] = (const float*)d_in[b + 5];
        fgp[l] = (const float*)d_in[b + 6];
        fbt[l] = (const float*)d_in[b + 7];
    }
    const float* cw = (const float*)d_in[27];
    const float* cb = (const float*)d_in[28];

    char* p = (char*)d_ws;
    auto carve = [&](size_t bytes) -> char* {
        char* r = p; p += (bytes + 255) & ~(size_t)255; return r;
    };
    float* xA   = (float*)carve((size_t)N * HD * 4);
    float* xB   = (float*)carve((size_t)N * HD * 4);
    unsigned short* hbuf = (unsigned short*)carve((size_t)N * HD * 2);   // bf16 h
    float* als  = (float*)carve((size_t)N * 4 * 4);
    float* ald  = (float*)carve((size_t)N * 4 * 4);
    int* rp   = (int*)carve((size_t)(N + 1) * 4);
    int* deg  = (int*)carve((size_t)N * 4);
    int* cur  = (int*)carve((size_t)N * 4);
    int* bsum = (int*)carve(4096);
    int* col  = (int*)carve((size_t)Etot * 4);
    unsigned short* wT[3];
    for (int l = 0; l < 3; l++) {
        int K = (l == 0) ? 512 : HD;
        wT[l] = (unsigned short*)carve((size_t)256 * K * 2);
    }

    // ---- weight cast+transpose+concat (tiny) ----
    for (int l = 0; l < 3; l++) {
        int K = (l == 0) ? 512 : HD;
        int nt = K * 256;
        prep_w2<<<(nt + 255) / 256, 256, 0, stream>>>(gw[l], fw[l], wT[l], K);
    }

    // ---- CSR by dst ----
    hipMemsetAsync(deg, 0, (size_t)N * 4, stream);
    hist_kernel<<<(Etot + 255) / 256, 256, 0, stream>>>(ei, E, N, deg);
    int nb = (N + 1023) / 1024;
    scan1<<<nb, 256, 0, stream>>>(deg, rp, bsum, N);
    scan2<<<1, 64, 0, stream>>>(bsum, nb);
    scan3<<<(N + 256) / 256, 256, 0, stream>>>(rp, cur, bsum, N, Etot);
    scatter_kernel<<<(Etot + 255) / 256, 256, 0, stream>>>(ei, E, N, cur, col);

    // ---- 3 message-passing layers ----
    for (int l = 0; l < 3; l++) {
        const float* xin = (l == 0) ? x0 : ((l == 1) ? xA : xB);
        float* xout = (l == 1) ? xB : xA;
        int K = (l == 0) ? 512 : HD;
        int mblocks = (N + 127) / 128;
        gemm_dual<<<mblocks, 512, 0, stream>>>(xin, wT[l], hbuf, xout, N, K,
                                               fbp[l], fgp[l], fbt[l], gbp[l]);
        al_kernel<<<(N * 4 + 255) / 256, 256, 0, stream>>>(hbuf, gas[l], gad[l], als, ald, N);
        agg_kernel<<<(N + 3) / 4, 256, 0, stream>>>(hbuf, als, ald, rp, col, xout, N);
    }

    // ---- classifier ----
    cls_kernel<<<(N + 3) / 4, 256, 0, stream>>>(xA, cw, cb, (float*)d_out, N);
}